// Round 1
// baseline (321.637 us; speedup 1.0000x reference)
//
#include <hip/hip_runtime.h>
#include <hip/hip_bf16.h>

#define B_N 16
#define L_N 9216
#define LT64 144    // L_N / 64

typedef __attribute__((ext_vector_type(8))) short short8;
typedef __attribute__((ext_vector_type(4))) float floatx4;

__device__ __forceinline__ float bfu(unsigned short u) {
  return __uint_as_float(((unsigned int)u) << 16);
}
__device__ __forceinline__ unsigned short fbf(float f) {
  __hip_bfloat16 h = __float2bfloat16(f);
  return *(unsigned short*)&h;
}

// ---------------------------------------------------------------------------
// K0: weights fp32 -> bf16
// ---------------------------------------------------------------------------
__global__ __launch_bounds__(256) void k_prep(const float* __restrict__ w1,
                                              const float* __restrict__ w2,
                                              __hip_bfloat16* __restrict__ w1bt,
                                              __hip_bfloat16* __restrict__ w2bt) {
  int i = blockIdx.x * 256 + threadIdx.x;
  if (i < 256 * 128) w1bt[i] = __float2bfloat16(w1[i]);
  if (i < 128 * 128) w2bt[i] = __float2bfloat16(w2[i]);
}

// ---------------------------------------------------------------------------
// K1 (fused, k_xt eliminated): in_proj MFMA (M=256e x N=64l x K=128c) reading
// x fp32 NCHW directly.  Stage bf16 [c][l] tile (l0-8..l0+63) in LDS (st),
// gather-transpose into swizzled MFMA B-tile xs [64 l][128 c].  Left conv
// boundary (3 cols) dotted from st (LDS broadcast) instead of global.
// st aliases cvs (dead before cvs first write; barrier separates).
// Then depthwise conv(k=4) + SiLU + x_proj as before.
// Outputs: zb bf16 (b,d,l), xinb bf16 (b,d,l), xdblT fp32 (b,12,L).
// ---------------------------------------------------------------------------
__global__ __launch_bounds__(256) void k_inproj_conv(
    const float* __restrict__ x, const __hip_bfloat16* __restrict__ w1bt,
    const float* __restrict__ cw, const float* __restrict__ cb,
    const float* __restrict__ xpw,
    __hip_bfloat16* __restrict__ xinb, __hip_bfloat16* __restrict__ zb,
    float* __restrict__ xdblT) {
  // region1 (16KB): xs (MFMA B tile) ; later red (12KB) aliases
  // region2 (34.8KB): st bf16 [128][73] (18.7KB) ; later cvs fp32 [128][68]
  __shared__ __align__(16) char smem1[16384];
  __shared__ __align__(16) char smem2[34816];
  __hip_bfloat16* xs = (__hip_bfloat16*)smem1;          // swizzled [64][128]
  float (*red)[12][64] = (float(*)[12][64])smem1;       // [4][12][64]
  unsigned short (*st)[73] = (unsigned short(*)[73])smem2; // [c][l0-8..l0+63]
  float (*cvs)[68] = (float(*)[68])smem2;               // conv staging [d][3+64+1]

  int blk = blockIdx.x, b = blk / LT64, lt = blk % LT64, l0 = lt * 64;
  int t = threadIdx.x;

  // ---- stage x fp32 -> st bf16 [c][l], 72 cols = l0-8 .. l0+63 ----
  const float* xb = x + (size_t)b * 128 * L_N + (l0 - 8);
#pragma unroll
  for (int i = 0; i < 9; ++i) {
    int idx = t + i * 256;            // 2304 float4 tasks: 128 c x 18 quads
    int c = idx / 18, q = idx % 18;
    float4 v;
    if (lt == 0 && q < 2) { v.x = 0.f; v.y = 0.f; v.z = 0.f; v.w = 0.f; }
    else v = *(const float4*)(xb + (size_t)c * L_N + q * 4);
    st[c][q * 4 + 0] = fbf(v.x); st[c][q * 4 + 1] = fbf(v.y);
    st[c][q * 4 + 2] = fbf(v.z); st[c][q * 4 + 3] = fbf(v.w);
  }

  int lane = t & 63, wv = t >> 6;
  int col = lane & 15, quad = lane >> 4;
  int e0 = wv * 64;
  // A fragments from global (L2-hot) — overlap with staging latency
  short8 afr[4][4];
  const __hip_bfloat16* wb = w1bt + (size_t)(e0 + col) * 128 + quad * 8;
#pragma unroll
  for (int mi = 0; mi < 4; ++mi)
#pragma unroll
    for (int ks = 0; ks < 4; ++ks)
      afr[mi][ks] = *(const short8*)(wb + mi * 16 * 128 + ks * 32);

  __syncthreads();                               // B0: st ready

  // ---- gather-transpose st -> xs (swizzled MFMA B tile) ----
#pragma unroll
  for (int p = 0; p < 4; ++p) {
    int gi = t + p * 256;             // 1024 tasks: 64 l x 16 chunks
    int l = gi >> 4, ch = gi & 15;
    short8 cc;
#pragma unroll
    for (int j = 0; j < 8; ++j) cc[j] = (short)st[ch * 8 + j][8 + l];
    *(short8*)&xs[l * 128 + ((ch ^ (l & 7)) * 8)] = cc;
  }

  floatx4 vzero = {0.f, 0.f, 0.f, 0.f};
  floatx4 acc[4][4];
#pragma unroll
  for (int mi = 0; mi < 4; ++mi)
#pragma unroll
    for (int ni = 0; ni < 4; ++ni) acc[mi][ni] = vzero;
  __syncthreads();                               // B1: xs ready

#pragma unroll
  for (int ks = 0; ks < 4; ++ks) {
    short8 bfr[4];
#pragma unroll
    for (int ni = 0; ni < 4; ++ni) {
      int row = ni * 16 + col;
      bfr[ni] = *(const short8*)&xs[row * 128 + (((ks * 4 + quad) ^ (row & 7)) * 8)];
    }
#pragma unroll
    for (int mi = 0; mi < 4; ++mi)
#pragma unroll
      for (int ni = 0; ni < 4; ++ni)
        acc[mi][ni] = __builtin_amdgcn_mfma_f32_16x16x32_bf16(afr[mi][ks], bfr[ni], acc[mi][ni], 0, 0, 0);
  }

  // left-boundary xinpre (3 columns) via dots reading st (LDS broadcast)
  float s0 = 0.f, s1 = 0.f, s2 = 0.f;
  if (t < 128 && lt > 0) {
    const __hip_bfloat16* wr = w1bt + (size_t)t * 128;
#pragma unroll
    for (int c8 = 0; c8 < 16; ++c8) {
      short8 wc = *(const short8*)(wr + c8 * 8);
#pragma unroll
      for (int e = 0; e < 8; ++e) {
        int c = c8 * 8 + e;
        float wf = bfu((unsigned short)wc[e]);
        s0 += wf * bfu(st[c][5]);   // l0-3
        s1 += wf * bfu(st[c][6]);   // l0-2
        s2 += wf * bfu(st[c][7]);   // l0-1
      }
    }
  }
  // z-half -> global bf16 (no LDS touched: safe before B2)
  if (wv >= 2) {
    __hip_bfloat16* zbase = zb + ((size_t)b * 128 + (e0 - 128)) * L_N + l0;
#pragma unroll
    for (int mi = 0; mi < 4; ++mi)
#pragma unroll
      for (int r = 0; r < 4; ++r) {
        int dr = mi * 16 + quad * 4 + r;
#pragma unroll
        for (int ni = 0; ni < 4; ++ni)
          zbase[(size_t)dr * L_N + ni * 16 + col] = __float2bfloat16(acc[mi][ni][r]);
      }
  }
  __syncthreads();                               // B2: st reads done, st dead

  // d-half -> cvs ; boundary cols 0..2
  if (t < 128) { cvs[t][0] = s0; cvs[t][1] = s1; cvs[t][2] = s2; }
  if (wv < 2) {
#pragma unroll
    for (int mi = 0; mi < 4; ++mi)
#pragma unroll
      for (int r = 0; r < 4; ++r) {
        int d = e0 + mi * 16 + quad * 4 + r;
#pragma unroll
        for (int ni = 0; ni < 4; ++ni) cvs[d][3 + ni * 16 + col] = acc[mi][ni][r];
      }
  }
  __syncthreads();                               // B3: cvs ready (xs dead)

  // conv + SiLU + x_proj partials; wave wv owns d in [wv*32, wv*32+32)
  float part[12];
#pragma unroll
  for (int m = 0; m < 12; ++m) part[m] = 0.f;
  for (int dd = 0; dd < 32; ++dd) {
    int d = wv * 32 + dd;
    float v = cb[d] + cw[d * 4 + 0] * cvs[d][lane] + cw[d * 4 + 1] * cvs[d][lane + 1]
                    + cw[d * 4 + 2] * cvs[d][lane + 2] + cw[d * 4 + 3] * cvs[d][lane + 3];
    v = v / (1.f + __expf(-v));                  // SiLU
    xinb[((size_t)b * 128 + d) * L_N + l0 + lane] = __float2bfloat16(v);
#pragma unroll
    for (int m = 0; m < 12; ++m) part[m] += xpw[m * 128 + d] * v;
  }
#pragma unroll
  for (int m = 0; m < 12; ++m) red[wv][m][lane] = part[m];
  __syncthreads();                               // B4
  for (int idx = t; idx < 12 * 64; idx += 256) {
    int m = idx >> 6, l = idx & 63;
    float s = red[0][m][l] + red[1][m][l] + red[2][m][l] + red[3][m][l];
    xdblT[((size_t)b * 12 + m) * L_N + l0 + l] = s;
  }
}

// ---------------------------------------------------------------------------
// K3: dt_proj + softplus + scan (D_STATE=2) + y + z-gate.
// Block per (b,d); 9 tiles of 1024 l; 4 elems/lane serial scan + wave KS on
// lane aggregates + cross-wave LDS agg + block-serial carry.
// ---------------------------------------------------------------------------
__global__ __launch_bounds__(256) void k_scan(
    const float* __restrict__ xdblT, const float* __restrict__ dtw,
    const float* __restrict__ dtb, const float* __restrict__ alog,
    const float* __restrict__ dpar,
    const __hip_bfloat16* __restrict__ xinb, const __hip_bfloat16* __restrict__ zb,
    __hip_bfloat16* __restrict__ yb) {
  __shared__ float agg[4][4];
  __shared__ float carry[2];
  int blk = blockIdx.x, b = blk >> 7, d = blk & 127;
  int t = threadIdx.x, lane = t & 63, wv = t >> 6;
  float A0 = -__expf(alog[2 * d]), A1 = -__expf(alog[2 * d + 1]);
  float Dv = dpar[d], dtbv = dtb[d];
  float w[8];
#pragma unroll
  for (int i = 0; i < 8; ++i) w[i] = dtw[d * 8 + i];
  if (t == 0) { carry[0] = 0.f; carry[1] = 0.f; }
  __syncthreads();
  const float* xdT = xdblT + (size_t)b * 12 * L_N;
  const unsigned short* xi = (const unsigned short*)xinb + ((size_t)b * 128 + d) * L_N;
  const unsigned short* zr = (const unsigned short*)zb + ((size_t)b * 128 + d) * L_N;
  unsigned short* yo = (unsigned short*)yb + ((size_t)b * 128 + d) * L_N;
  for (int it = 0; it < 9; ++it) {
    int lb = it * 1024 + t * 4;
    float4 q[12];
#pragma unroll
    for (int m = 0; m < 12; ++m) q[m] = *(const float4*)(xdT + (size_t)m * L_N + lb);
    ushort4 xu = *(const ushort4*)(xi + lb);
    ushort4 zu = *(const ushort4*)(zr + lb);
    float xv[4] = {bfu(xu.x), bfu(xu.y), bfu(xu.z), bfu(xu.w)};
    float zv[4] = {bfu(zu.x), bfu(zu.y), bfu(zu.z), bfu(zu.w)};
    float A0p[4], X0p[4], A1p[4], X1p[4];
#pragma unroll
    for (int j = 0; j < 4; ++j) {
      float dtp = dtbv;
#pragma unroll
      for (int m = 0; m < 8; ++m) dtp += w[m] * ((const float*)&q[m])[j];
      float dt = (dtp > 15.f) ? dtp : __logf(1.f + __expf(dtp));  // softplus
      float a0 = __expf(dt * A0), a1 = __expf(dt * A1);
      float dtx = dt * xv[j];
      float x0 = dtx * ((const float*)&q[8])[j];
      float x1 = dtx * ((const float*)&q[9])[j];
      if (j == 0) { A0p[0] = a0; X0p[0] = x0; A1p[0] = a1; X1p[0] = x1; }
      else {
        A0p[j] = a0 * A0p[j - 1]; X0p[j] = a0 * X0p[j - 1] + x0;
        A1p[j] = a1 * A1p[j - 1]; X1p[j] = a1 * X1p[j - 1] + x1;
      }
    }
    float wA0 = A0p[3], wX0 = X0p[3], wA1 = A1p[3], wX1 = X1p[3];
#pragma unroll
    for (int off = 1; off < 64; off <<= 1) {
      float pA0 = __shfl_up(wA0, off, 64), pX0 = __shfl_up(wX0, off, 64);
      float pA1 = __shfl_up(wA1, off, 64), pX1 = __shfl_up(wX1, off, 64);
      if (lane >= off) {
        wX0 += wA0 * pX0; wA0 *= pA0;
        wX1 += wA1 * pX1; wA1 *= pA1;
      }
    }
    if (lane == 63) { agg[wv][0] = wA0; agg[wv][1] = wX0; agg[wv][2] = wA1; agg[wv][3] = wX1; }
    float eA0 = __shfl_up(wA0, 1, 64), eX0 = __shfl_up(wX0, 1, 64);
    float eA1 = __shfl_up(wA1, 1, 64), eX1 = __shfl_up(wX1, 1, 64);
    if (lane == 0) { eA0 = 1.f; eX0 = 0.f; eA1 = 1.f; eX1 = 0.f; }
    __syncthreads();
    float h0 = carry[0], h1 = carry[1];
    for (int jw = 0; jw < wv; ++jw) {            // wave-uniform
      h0 = agg[jw][0] * h0 + agg[jw][1];
      h1 = agg[jw][2] * h1 + agg[jw][3];
    }
    h0 = eA0 * h0 + eX0;                         // lane input state
    h1 = eA1 * h1 + eX1;
    __syncthreads();
    if (t == 255) { carry[0] = A0p[3] * h0 + X0p[3]; carry[1] = A1p[3] * h1 + X1p[3]; }
    ushort4 yu;
    unsigned short* yp = (unsigned short*)&yu;
#pragma unroll
    for (int j = 0; j < 4; ++j) {
      float hh0 = A0p[j] * h0 + X0p[j];
      float hh1 = A1p[j] * h1 + X1p[j];
      float y = hh0 * ((const float*)&q[10])[j] + hh1 * ((const float*)&q[11])[j] + Dv * xv[j];
      y *= zv[j] / (1.f + __expf(-zv[j]));
      yp[j] = fbf(y);
    }
    *(ushort4*)(yo + lb) = yu;
  }
}

// ---------------------------------------------------------------------------
// K4: out_proj MFMA (M=128o x N=64l x K=128d) + LayerNorm + NCHW write.
// y bf16 (b,d,l) staged [d][l] in LDS, gather-packed into swizzled [l][d]
// MFMA-B tile.  w2 A-fragments direct from global (L2-hot).
// ---------------------------------------------------------------------------
__global__ __launch_bounds__(256) void k_outln(
    const __hip_bfloat16* __restrict__ yb, const __hip_bfloat16* __restrict__ w2bt,
    const float* __restrict__ gam, const float* __restrict__ bet,
    float* __restrict__ out) {
  __shared__ unsigned short st[128][68];
  __shared__ __hip_bfloat16 yts[64 * 128];
  __shared__ float red_s[4][64], red_q[4][64];
  __shared__ float gs[128], bs[128];
  int blk = blockIdx.x, b = blk / LT64, lt = blk % LT64, l0 = lt * 64;
  int t = threadIdx.x;
  if (t < 128) { gs[t] = gam[t]; bs[t] = bet[t]; }
  const unsigned short* ybb = (const unsigned short*)yb + (size_t)b * 128 * L_N + l0;
#pragma unroll
  for (int i = 0; i < 8; ++i) {
    int idx = t + i * 256;              // 2048 ushort4 loads (128d x 16 l-quads)
    int dd = idx >> 4, l4 = (idx & 15) * 4;
    ushort4 v = *(const ushort4*)(ybb + (size_t)dd * L_N + l4);
    *(ushort4*)&st[dd][l4] = v;
  }
  __syncthreads();
#pragma unroll
  for (int p = 0; p < 4; ++p) {
    int gi = t + p * 256;               // 1024 chunk-packs (64 l x 16 ch)
    int l = gi & 63, ch = gi >> 6;
    short8 c;
#pragma unroll
    for (int j = 0; j < 8; ++j) c[j] = (short)st[ch * 8 + j][l];
    *(short8*)&yts[l * 128 + ((ch ^ (l & 7)) * 8)] = c;
  }
  int lane = t & 63, wv = t >> 6;
  int col = lane & 15, quad = lane >> 4;
  int o0 = wv * 32;
  short8 afr[2][4];
#pragma unroll
  for (int mi = 0; mi < 2; ++mi)
#pragma unroll
    for (int ks = 0; ks < 4; ++ks)
      afr[mi][ks] = *(const short8*)(w2bt + (size_t)(o0 + mi * 16 + col) * 128 + ks * 32 + quad * 8);
  floatx4 vzero = {0.f, 0.f, 0.f, 0.f};
  floatx4 acc[2][4];
#pragma unroll
  for (int mi = 0; mi < 2; ++mi)
#pragma unroll
    for (int ni = 0; ni < 4; ++ni) acc[mi][ni] = vzero;
  __syncthreads();
#pragma unroll
  for (int ks = 0; ks < 4; ++ks) {
    short8 bfr[4];
#pragma unroll
    for (int ni = 0; ni < 4; ++ni) {
      int row = ni * 16 + col;
      bfr[ni] = *(const short8*)&yts[row * 128 + (((ks * 4 + quad) ^ (row & 7)) * 8)];
    }
#pragma unroll
    for (int mi = 0; mi < 2; ++mi)
#pragma unroll
      for (int ni = 0; ni < 4; ++ni)
        acc[mi][ni] = __builtin_amdgcn_mfma_f32_16x16x32_bf16(afr[mi][ks], bfr[ni], acc[mi][ni], 0, 0, 0);
  }
  float s[4], q[4];
#pragma unroll
  for (int ni = 0; ni < 4; ++ni) {
    float ss = 0.f, qq = 0.f;
#pragma unroll
    for (int mi = 0; mi < 2; ++mi)
#pragma unroll
      for (int r = 0; r < 4; ++r) {
        float v = acc[mi][ni][r];
        ss += v; qq += v * v;
      }
    ss += __shfl_xor(ss, 16, 64); ss += __shfl_xor(ss, 32, 64);
    qq += __shfl_xor(qq, 16, 64); qq += __shfl_xor(qq, 32, 64);
    s[ni] = ss; q[ni] = qq;
  }
  if (quad == 0) {
#pragma unroll
    for (int ni = 0; ni < 4; ++ni) {
      red_s[wv][ni * 16 + col] = s[ni];
      red_q[wv][ni * 16 + col] = q[ni];
    }
  }
  __syncthreads();
  float mu[4], rstd[4];
#pragma unroll
  for (int ni = 0; ni < 4; ++ni) {
    int li = ni * 16 + col;
    float ts = red_s[0][li] + red_s[1][li] + red_s[2][li] + red_s[3][li];
    float tq = red_q[0][li] + red_q[1][li] + red_q[2][li] + red_q[3][li];
    float m = ts * (1.f / 128.f);
    float var = tq * (1.f / 128.f) - m * m;
    mu[ni] = m;
    rstd[ni] = rsqrtf(var + 1e-5f);
  }
  float* ob = out + (size_t)b * 128 * L_N;
#pragma unroll
  for (int mi = 0; mi < 2; ++mi)
#pragma unroll
    for (int r = 0; r < 4; ++r) {
      int o = o0 + mi * 16 + quad * 4 + r;
      float g = gs[o], bb = bs[o];
#pragma unroll
      for (int ni = 0; ni < 4; ++ni)
        ob[(size_t)o * L_N + l0 + ni * 16 + col] = (acc[mi][ni][r] - mu[ni]) * rstd[ni] * g + bb;
    }
}

// ---------------------------------------------------------------------------
extern "C" void kernel_launch(void* const* d_in, const int* in_sizes, int n_in,
                              void* d_out, int out_size, void* d_ws, size_t ws_size,
                              hipStream_t stream) {
  const float* x    = (const float*)d_in[0];
  const float* w1   = (const float*)d_in[1];
  const float* cw   = (const float*)d_in[2];
  const float* cb   = (const float*)d_in[3];
  const float* xpw  = (const float*)d_in[4];
  const float* dtw  = (const float*)d_in[5];
  const float* dtb  = (const float*)d_in[6];
  const float* alog = (const float*)d_in[7];
  const float* dpar = (const float*)d_in[8];
  const float* w2   = (const float*)d_in[9];
  const float* gam  = (const float*)d_in[10];
  const float* bet  = (const float*)d_in[11];
  float* out = (float*)d_out;

  float* ws = (float*)d_ws;
  const size_t NBL = (size_t)B_N * 128 * L_N;      // 18,874,368
  float* xdblT = ws;                                // fp32 (B,12,L)
  __hip_bfloat16* xinb = (__hip_bfloat16*)(ws + (size_t)B_N * 12 * L_N);
  __hip_bfloat16* zb   = xinb + NBL;                // bf16 (B,D,L)
  __hip_bfloat16* yb   = zb + NBL;                  // bf16 (B,D,L)
  __hip_bfloat16* w1bt = yb + NBL;
  __hip_bfloat16* w2bt = w1bt + 256 * 128;

  k_prep<<<128, 256, 0, stream>>>(w1, w2, w1bt, w2bt);
  k_inproj_conv<<<B_N * LT64, 256, 0, stream>>>(x, w1bt, cw, cb, xpw, xinb, zb, xdblT);
  k_scan<<<B_N * 128, 256, 0, stream>>>(xdblT, dtw, dtb, alog, dpar, xinb, zb, yb);
  k_outln<<<B_N * LT64, 256, 0, stream>>>(yb, w2bt, gam, bet, out);
}

// Round 2
// 309.779 us; speedup vs baseline: 1.0383x; 1.0383x over previous
//
#include <hip/hip_runtime.h>
#include <hip/hip_bf16.h>

#define B_N 16
#define L_N 9216
#define LT64 144    // L_N / 64

typedef __attribute__((ext_vector_type(8))) short short8;
typedef __attribute__((ext_vector_type(4))) float floatx4;

__device__ __forceinline__ float bfu(unsigned short u) {
  return __uint_as_float(((unsigned int)u) << 16);
}
__device__ __forceinline__ unsigned short fbf(float f) {
  __hip_bfloat16 h = __float2bfloat16(f);
  return *(unsigned short*)&h;
}

// ---------------------------------------------------------------------------
// K0: weights fp32 -> bf16
// ---------------------------------------------------------------------------
__global__ __launch_bounds__(256) void k_prep(const float* __restrict__ w1,
                                              const float* __restrict__ w2,
                                              __hip_bfloat16* __restrict__ w1bt,
                                              __hip_bfloat16* __restrict__ w2bt) {
  int i = blockIdx.x * 256 + threadIdx.x;
  if (i < 256 * 128) w1bt[i] = __float2bfloat16(w1[i]);
  if (i < 128 * 128) w2bt[i] = __float2bfloat16(w2[i]);
}

// ---------------------------------------------------------------------------
// K1: in_proj MFMA (M=256e x N=64l x K=128c) reading x fp32 NCHW directly.
// Staging scatters bf16 DIRECTLY into the swizzled MFMA B-tile xs (no gather
// phase).  Halo (l0-8..l0-1) goes to a c-contiguous buffer so the left conv
// boundary dot is 48 vector LDS broadcasts.  Conv epilogue runs in two 64-d
// phases so cvs is half-size -> 33.8KB LDS -> 4 blocks/CU.
// Outputs: zb bf16 (b,d,l), xinb bf16 (b,d,l), xdblT fp32 (b,12,L).
// ---------------------------------------------------------------------------
__global__ __launch_bounds__(256) void k_inproj_conv(
    const float* __restrict__ x, const __hip_bfloat16* __restrict__ w1bt,
    const float* __restrict__ cw, const float* __restrict__ cb,
    const float* __restrict__ xpw,
    __hip_bfloat16* __restrict__ xinb, __hip_bfloat16* __restrict__ zb,
    float* __restrict__ xdblT) {
  // smem1 16KB: xs swizzled B-tile [64 l][128 c] bf16 ; later red[4][12][64]
  // smem2 17KB: halo[8][128] bf16 (c-contig) ; later cvs[64][68] fp32
  __shared__ __align__(16) char smem1[16384];
  __shared__ __align__(16) char smem2[17408];
  unsigned short* xs = (unsigned short*)smem1;
  float (*red)[12][64] = (float(*)[12][64])smem1;
  unsigned short (*halo)[128] = (unsigned short(*)[128])smem2;
  float (*cvs)[68] = (float(*)[68])smem2;

  int blk = blockIdx.x, b = blk / LT64, lt = blk % LT64, l0 = lt * 64;
  int t = threadIdx.x;
  int lane = t & 63, wv = t >> 6;
  int col = lane & 15, quad = lane >> 4;
  int e0 = wv * 64;

  // ---- stage x fp32 -> bf16, scattered into xs (swizzled) + halo ----
  // c-fast mapping: per write instruction 64 lanes hit all 32 banks (free).
  const float* xb = x + (size_t)b * 128 * L_N + (l0 - 8);
#pragma unroll
  for (int i = 0; i < 9; ++i) {
    int idx = t + i * 256;
    int c = idx & 127, q = idx >> 7;   // q wave-uniform
    if (q == 0) continue;              // l0-8..l0-5 never consumed
    float4 v;
    if (lt == 0 && q < 2) { v.x = 0.f; v.y = 0.f; v.z = 0.f; v.w = 0.f; }
    else v = *(const float4*)(xb + (size_t)c * L_N + q * 4);
    if (q < 2) {
      halo[4][c] = fbf(v.x); halo[5][c] = fbf(v.y);
      halo[6][c] = fbf(v.z); halo[7][c] = fbf(v.w);
    } else {
      int l = q * 4 - 8;
      xs[(l + 0) * 128 + ((((c >> 3) ^ ((l + 0) & 7)) << 3) | (c & 7))] = fbf(v.x);
      xs[(l + 1) * 128 + ((((c >> 3) ^ ((l + 1) & 7)) << 3) | (c & 7))] = fbf(v.y);
      xs[(l + 2) * 128 + ((((c >> 3) ^ ((l + 2) & 7)) << 3) | (c & 7))] = fbf(v.z);
      xs[(l + 3) * 128 + ((((c >> 3) ^ ((l + 3) & 7)) << 3) | (c & 7))] = fbf(v.w);
    }
  }

  // A fragments from global (L2-hot) — overlaps staging latency
  short8 afr[4][4];
  const __hip_bfloat16* wbp = w1bt + (size_t)(e0 + col) * 128 + quad * 8;
#pragma unroll
  for (int mi = 0; mi < 4; ++mi)
#pragma unroll
    for (int ks = 0; ks < 4; ++ks)
      afr[mi][ks] = *(const short8*)(wbp + mi * 16 * 128 + ks * 32);

  floatx4 vzero = {0.f, 0.f, 0.f, 0.f};
  floatx4 acc[4][4];
#pragma unroll
  for (int mi = 0; mi < 4; ++mi)
#pragma unroll
    for (int ni = 0; ni < 4; ++ni) acc[mi][ni] = vzero;
  __syncthreads();                               // B1: xs + halo ready

#pragma unroll
  for (int ks = 0; ks < 4; ++ks) {
    short8 bfr[4];
#pragma unroll
    for (int ni = 0; ni < 4; ++ni) {
      int row = ni * 16 + col;
      bfr[ni] = *(const short8*)&xs[row * 128 + (((ks * 4 + quad) ^ (row & 7)) << 3)];
    }
#pragma unroll
    for (int mi = 0; mi < 4; ++mi)
#pragma unroll
      for (int ni = 0; ni < 4; ++ni)
        acc[mi][ni] = __builtin_amdgcn_mfma_f32_16x16x32_bf16(afr[mi][ks], bfr[ni], acc[mi][ni], 0, 0, 0);
  }

  // left-boundary conv inputs (3 columns) — vector LDS broadcasts from halo
  float s0 = 0.f, s1 = 0.f, s2 = 0.f;
  if (t < 128 && lt > 0) {
    const __hip_bfloat16* wr = w1bt + (size_t)t * 128;
#pragma unroll
    for (int c8 = 0; c8 < 16; ++c8) {
      short8 wc = *(const short8*)(wr + c8 * 8);
      short8 h5 = *(const short8*)&halo[5][c8 * 8];
      short8 h6 = *(const short8*)&halo[6][c8 * 8];
      short8 h7 = *(const short8*)&halo[7][c8 * 8];
#pragma unroll
      for (int e = 0; e < 8; ++e) {
        float wf = bfu((unsigned short)wc[e]);
        s0 += wf * bfu((unsigned short)h5[e]);
        s1 += wf * bfu((unsigned short)h6[e]);
        s2 += wf * bfu((unsigned short)h7[e]);
      }
    }
  }

  // z-half -> global bf16 (no LDS: safe before B2)
  if (wv >= 2) {
    __hip_bfloat16* zbase = zb + ((size_t)b * 128 + (e0 - 128)) * L_N + l0;
#pragma unroll
    for (int mi = 0; mi < 4; ++mi)
#pragma unroll
      for (int r = 0; r < 4; ++r) {
        int dr = mi * 16 + quad * 4 + r;
#pragma unroll
        for (int ni = 0; ni < 4; ++ni)
          zbase[(size_t)dr * L_N + ni * 16 + col] = __float2bfloat16(acc[mi][ni][r]);
      }
  }
  __syncthreads();                     // B2: halo + xs reads done

  // ---- phase A: d 0..63 ----
  if (t < 64) { cvs[t][0] = s0; cvs[t][1] = s1; cvs[t][2] = s2; }
  if (wv == 0) {
#pragma unroll
    for (int mi = 0; mi < 4; ++mi)
#pragma unroll
      for (int r = 0; r < 4; ++r) {
        int d = mi * 16 + quad * 4 + r;
#pragma unroll
        for (int ni = 0; ni < 4; ++ni) cvs[d][3 + ni * 16 + col] = acc[mi][ni][r];
      }
  }
  __syncthreads();                     // B3: cvs(A) ready

  float part[12];
#pragma unroll
  for (int m = 0; m < 12; ++m) part[m] = 0.f;
  for (int dd = 0; dd < 16; ++dd) {
    int d = wv * 16 + dd;
    float v = cb[d] + cw[d * 4 + 0] * cvs[d][lane] + cw[d * 4 + 1] * cvs[d][lane + 1]
                    + cw[d * 4 + 2] * cvs[d][lane + 2] + cw[d * 4 + 3] * cvs[d][lane + 3];
    v = v / (1.f + __expf(-v));                  // SiLU
    xinb[((size_t)b * 128 + d) * L_N + l0 + lane] = __float2bfloat16(v);
#pragma unroll
    for (int m = 0; m < 12; ++m) part[m] += xpw[m * 128 + d] * v;
  }
  __syncthreads();                     // B4: phase-A conv reads done

  // ---- phase B: d 64..127 ----
  if (t >= 64 && t < 128) { cvs[t - 64][0] = s0; cvs[t - 64][1] = s1; cvs[t - 64][2] = s2; }
  if (wv == 1) {
#pragma unroll
    for (int mi = 0; mi < 4; ++mi)
#pragma unroll
      for (int r = 0; r < 4; ++r) {
        int rr = mi * 16 + quad * 4 + r;
#pragma unroll
        for (int ni = 0; ni < 4; ++ni) cvs[rr][3 + ni * 16 + col] = acc[mi][ni][r];
      }
  }
  __syncthreads();                     // B5: cvs(B) ready

  for (int dd = 0; dd < 16; ++dd) {
    int rr = wv * 16 + dd, d = 64 + rr;
    float v = cb[d] + cw[d * 4 + 0] * cvs[rr][lane] + cw[d * 4 + 1] * cvs[rr][lane + 1]
                    + cw[d * 4 + 2] * cvs[rr][lane + 2] + cw[d * 4 + 3] * cvs[rr][lane + 3];
    v = v / (1.f + __expf(-v));                  // SiLU
    xinb[((size_t)b * 128 + d) * L_N + l0 + lane] = __float2bfloat16(v);
#pragma unroll
    for (int m = 0; m < 12; ++m) part[m] += xpw[m * 128 + d] * v;
  }
#pragma unroll
  for (int m = 0; m < 12; ++m) red[wv][m][lane] = part[m];
  __syncthreads();                     // B6
  for (int idx = t; idx < 12 * 64; idx += 256) {
    int m = idx >> 6, l = idx & 63;
    float s = red[0][m][l] + red[1][m][l] + red[2][m][l] + red[3][m][l];
    xdblT[((size_t)b * 12 + m) * L_N + l0 + l] = s;
  }
}

// ---------------------------------------------------------------------------
// K3: dt_proj + softplus + scan (D_STATE=2) + y + z-gate.
// Block per (b,d); 9 tiles of 1024 l; 4 elems/lane serial scan + wave KS on
// lane aggregates + cross-wave LDS agg + block-serial carry.
// ---------------------------------------------------------------------------
__global__ __launch_bounds__(256) void k_scan(
    const float* __restrict__ xdblT, const float* __restrict__ dtw,
    const float* __restrict__ dtb, const float* __restrict__ alog,
    const float* __restrict__ dpar,
    const __hip_bfloat16* __restrict__ xinb, const __hip_bfloat16* __restrict__ zb,
    __hip_bfloat16* __restrict__ yb) {
  __shared__ float agg[4][4];
  __shared__ float carry[2];
  int blk = blockIdx.x, b = blk >> 7, d = blk & 127;
  int t = threadIdx.x, lane = t & 63, wv = t >> 6;
  float A0 = -__expf(alog[2 * d]), A1 = -__expf(alog[2 * d + 1]);
  float Dv = dpar[d], dtbv = dtb[d];
  float w[8];
#pragma unroll
  for (int i = 0; i < 8; ++i) w[i] = dtw[d * 8 + i];
  if (t == 0) { carry[0] = 0.f; carry[1] = 0.f; }
  __syncthreads();
  const float* xdT = xdblT + (size_t)b * 12 * L_N;
  const unsigned short* xi = (const unsigned short*)xinb + ((size_t)b * 128 + d) * L_N;
  const unsigned short* zr = (const unsigned short*)zb + ((size_t)b * 128 + d) * L_N;
  unsigned short* yo = (unsigned short*)yb + ((size_t)b * 128 + d) * L_N;
  for (int it = 0; it < 9; ++it) {
    int lb = it * 1024 + t * 4;
    float4 q[12];
#pragma unroll
    for (int m = 0; m < 12; ++m) q[m] = *(const float4*)(xdT + (size_t)m * L_N + lb);
    ushort4 xu = *(const ushort4*)(xi + lb);
    ushort4 zu = *(const ushort4*)(zr + lb);
    float xv[4] = {bfu(xu.x), bfu(xu.y), bfu(xu.z), bfu(xu.w)};
    float zv[4] = {bfu(zu.x), bfu(zu.y), bfu(zu.z), bfu(zu.w)};
    float A0p[4], X0p[4], A1p[4], X1p[4];
#pragma unroll
    for (int j = 0; j < 4; ++j) {
      float dtp = dtbv;
#pragma unroll
      for (int m = 0; m < 8; ++m) dtp += w[m] * ((const float*)&q[m])[j];
      float dt = (dtp > 15.f) ? dtp : __logf(1.f + __expf(dtp));  // softplus
      float a0 = __expf(dt * A0), a1 = __expf(dt * A1);
      float dtx = dt * xv[j];
      float x0 = dtx * ((const float*)&q[8])[j];
      float x1 = dtx * ((const float*)&q[9])[j];
      if (j == 0) { A0p[0] = a0; X0p[0] = x0; A1p[0] = a1; X1p[0] = x1; }
      else {
        A0p[j] = a0 * A0p[j - 1]; X0p[j] = a0 * X0p[j - 1] + x0;
        A1p[j] = a1 * A1p[j - 1]; X1p[j] = a1 * X1p[j - 1] + x1;
      }
    }
    float wA0 = A0p[3], wX0 = X0p[3], wA1 = A1p[3], wX1 = X1p[3];
#pragma unroll
    for (int off = 1; off < 64; off <<= 1) {
      float pA0 = __shfl_up(wA0, off, 64), pX0 = __shfl_up(wX0, off, 64);
      float pA1 = __shfl_up(wA1, off, 64), pX1 = __shfl_up(wX1, off, 64);
      if (lane >= off) {
        wX0 += wA0 * pX0; wA0 *= pA0;
        wX1 += wA1 * pX1; wA1 *= pA1;
      }
    }
    if (lane == 63) { agg[wv][0] = wA0; agg[wv][1] = wX0; agg[wv][2] = wA1; agg[wv][3] = wX1; }
    float eA0 = __shfl_up(wA0, 1, 64), eX0 = __shfl_up(wX0, 1, 64);
    float eA1 = __shfl_up(wA1, 1, 64), eX1 = __shfl_up(wX1, 1, 64);
    if (lane == 0) { eA0 = 1.f; eX0 = 0.f; eA1 = 1.f; eX1 = 0.f; }
    __syncthreads();
    float h0 = carry[0], h1 = carry[1];
    for (int jw = 0; jw < wv; ++jw) {            // wave-uniform
      h0 = agg[jw][0] * h0 + agg[jw][1];
      h1 = agg[jw][2] * h1 + agg[jw][3];
    }
    h0 = eA0 * h0 + eX0;                         // lane input state
    h1 = eA1 * h1 + eX1;
    __syncthreads();
    if (t == 255) { carry[0] = A0p[3] * h0 + X0p[3]; carry[1] = A1p[3] * h1 + X1p[3]; }
    ushort4 yu;
    unsigned short* yp = (unsigned short*)&yu;
#pragma unroll
    for (int j = 0; j < 4; ++j) {
      float hh0 = A0p[j] * h0 + X0p[j];
      float hh1 = A1p[j] * h1 + X1p[j];
      float y = hh0 * ((const float*)&q[10])[j] + hh1 * ((const float*)&q[11])[j] + Dv * xv[j];
      y *= zv[j] / (1.f + __expf(-zv[j]));
      yp[j] = fbf(y);
    }
    *(ushort4*)(yo + lb) = yu;
  }
}

// ---------------------------------------------------------------------------
// K4: out_proj MFMA (M=128o x N=64l x K=128d) + LayerNorm + NCHW write.
// ---------------------------------------------------------------------------
__global__ __launch_bounds__(256) void k_outln(
    const __hip_bfloat16* __restrict__ yb, const __hip_bfloat16* __restrict__ w2bt,
    const float* __restrict__ gam, const float* __restrict__ bet,
    float* __restrict__ out) {
  __shared__ unsigned short st[128][68];
  __shared__ __hip_bfloat16 yts[64 * 128];
  __shared__ float red_s[4][64], red_q[4][64];
  __shared__ float gs[128], bs[128];
  int blk = blockIdx.x, b = blk / LT64, lt = blk % LT64, l0 = lt * 64;
  int t = threadIdx.x;
  if (t < 128) { gs[t] = gam[t]; bs[t] = bet[t]; }
  const unsigned short* ybb = (const unsigned short*)yb + (size_t)b * 128 * L_N + l0;
#pragma unroll
  for (int i = 0; i < 8; ++i) {
    int idx = t + i * 256;              // 2048 ushort4 loads (128d x 16 l-quads)
    int dd = idx >> 4, l4 = (idx & 15) * 4;
    ushort4 v = *(const ushort4*)(ybb + (size_t)dd * L_N + l4);
    *(ushort4*)&st[dd][l4] = v;
  }
  __syncthreads();
#pragma unroll
  for (int p = 0; p < 4; ++p) {
    int gi = t + p * 256;               // 1024 chunk-packs (64 l x 16 ch)
    int l = gi & 63, ch = gi >> 6;
    short8 c;
#pragma unroll
    for (int j = 0; j < 8; ++j) c[j] = (short)st[ch * 8 + j][l];
    *(short8*)&yts[l * 128 + ((ch ^ (l & 7)) * 8)] = c;
  }
  int lane = t & 63, wv = t >> 6;
  int col = lane & 15, quad = lane >> 4;
  int o0 = wv * 32;
  short8 afr[2][4];
#pragma unroll
  for (int mi = 0; mi < 2; ++mi)
#pragma unroll
    for (int ks = 0; ks < 4; ++ks)
      afr[mi][ks] = *(const short8*)(w2bt + (size_t)(o0 + mi * 16 + col) * 128 + ks * 32 + quad * 8);
  floatx4 vzero = {0.f, 0.f, 0.f, 0.f};
  floatx4 acc[2][4];
#pragma unroll
  for (int mi = 0; mi < 2; ++mi)
#pragma unroll
    for (int ni = 0; ni < 4; ++ni) acc[mi][ni] = vzero;
  __syncthreads();
#pragma unroll
  for (int ks = 0; ks < 4; ++ks) {
    short8 bfr[4];
#pragma unroll
    for (int ni = 0; ni < 4; ++ni) {
      int row = ni * 16 + col;
      bfr[ni] = *(const short8*)&yts[row * 128 + (((ks * 4 + quad) ^ (row & 7)) * 8)];
    }
#pragma unroll
    for (int mi = 0; mi < 2; ++mi)
#pragma unroll
      for (int ni = 0; ni < 4; ++ni)
        acc[mi][ni] = __builtin_amdgcn_mfma_f32_16x16x32_bf16(afr[mi][ks], bfr[ni], acc[mi][ni], 0, 0, 0);
  }
  float s[4], q[4];
#pragma unroll
  for (int ni = 0; ni < 4; ++ni) {
    float ss = 0.f, qq = 0.f;
#pragma unroll
    for (int mi = 0; mi < 2; ++mi)
#pragma unroll
      for (int r = 0; r < 4; ++r) {
        float v = acc[mi][ni][r];
        ss += v; qq += v * v;
      }
    ss += __shfl_xor(ss, 16, 64); ss += __shfl_xor(ss, 32, 64);
    qq += __shfl_xor(qq, 16, 64); qq += __shfl_xor(qq, 32, 64);
    s[ni] = ss; q[ni] = qq;
  }
  if (quad == 0) {
#pragma unroll
    for (int ni = 0; ni < 4; ++ni) {
      red_s[wv][ni * 16 + col] = s[ni];
      red_q[wv][ni * 16 + col] = q[ni];
    }
  }
  __syncthreads();
  float mu[4], rstd[4];
#pragma unroll
  for (int ni = 0; ni < 4; ++ni) {
    int li = ni * 16 + col;
    float ts = red_s[0][li] + red_s[1][li] + red_s[2][li] + red_s[3][li];
    float tq = red_q[0][li] + red_q[1][li] + red_q[2][li] + red_q[3][li];
    float m = ts * (1.f / 128.f);
    float var = tq * (1.f / 128.f) - m * m;
    mu[ni] = m;
    rstd[ni] = rsqrtf(var + 1e-5f);
  }
  float* ob = out + (size_t)b * 128 * L_N;
#pragma unroll
  for (int mi = 0; mi < 2; ++mi)
#pragma unroll
    for (int r = 0; r < 4; ++r) {
      int o = o0 + mi * 16 + quad * 4 + r;
      float g = gs[o], bb = bs[o];
#pragma unroll
      for (int ni = 0; ni < 4; ++ni)
        ob[(size_t)o * L_N + l0 + ni * 16 + col] = (acc[mi][ni][r] - mu[ni]) * rstd[ni] * g + bb;
    }
}

// ---------------------------------------------------------------------------
extern "C" void kernel_launch(void* const* d_in, const int* in_sizes, int n_in,
                              void* d_out, int out_size, void* d_ws, size_t ws_size,
                              hipStream_t stream) {
  const float* x    = (const float*)d_in[0];
  const float* w1   = (const float*)d_in[1];
  const float* cw   = (const float*)d_in[2];
  const float* cb   = (const float*)d_in[3];
  const float* xpw  = (const float*)d_in[4];
  const float* dtw  = (const float*)d_in[5];
  const float* dtb  = (const float*)d_in[6];
  const float* alog = (const float*)d_in[7];
  const float* dpar = (const float*)d_in[8];
  const float* w2   = (const float*)d_in[9];
  const float* gam  = (const float*)d_in[10];
  const float* bet  = (const float*)d_in[11];
  float* out = (float*)d_out;

  float* ws = (float*)d_ws;
  const size_t NBL = (size_t)B_N * 128 * L_N;      // 18,874,368
  float* xdblT = ws;                                // fp32 (B,12,L)
  __hip_bfloat16* xinb = (__hip_bfloat16*)(ws + (size_t)B_N * 12 * L_N);
  __hip_bfloat16* zb   = xinb + NBL;                // bf16 (B,D,L)
  __hip_bfloat16* yb   = zb + NBL;                  // bf16 (B,D,L)
  __hip_bfloat16* w1bt = yb + NBL;
  __hip_bfloat16* w2bt = w1bt + 256 * 128;

  k_prep<<<128, 256, 0, stream>>>(w1, w2, w1bt, w2bt);
  k_inproj_conv<<<B_N * LT64, 256, 0, stream>>>(x, w1bt, cw, cb, xpw, xinb, zb, xdblT);
  k_scan<<<B_N * 128, 256, 0, stream>>>(xdblT, dtw, dtb, alog, dpar, xinb, zb, yb);
  k_outln<<<B_N * LT64, 256, 0, stream>>>(yb, w2bt, gam, bet, out);
}